// Round 1
// baseline (3502.129 us; speedup 1.0000x reference)
//
#include <hip/hip_runtime.h>

#define T_STEPS 512
#define HID 64
#define SPB 8          // samples per block
#define NTHREADS 256

// 4 FMAs: acc += W[kk..kk+3] * (vx, vy, vz, vw)
#define FMA4(acc, W, V, kk)                                 \
    acc = fmaf(W[(kk)+0], V.x, acc);                        \
    acc = fmaf(W[(kk)+1], V.y, acc);                        \
    acc = fmaf(W[(kk)+2], V.z, acc);                        \
    acc = fmaf(W[(kk)+3], V.w, acc);

__global__ __launch_bounds__(NTHREADS, 1)
void gru2_fp32(const float* __restrict__ state,
               const float* __restrict__ w_ih1, const float* __restrict__ w_hh1,
               const float* __restrict__ b_ih1, const float* __restrict__ b_hh1,
               const float* __restrict__ w_ih2, const float* __restrict__ w_hh2,
               const float* __restrict__ b_ih2, const float* __restrict__ b_hh2,
               const float* __restrict__ fc_w,  const float* __restrict__ fc_b,
               float* __restrict__ out)
{
    // x double-buffered; partial gate sums per (wave, sample, j); hidden states.
    __shared__ __align__(16) float  xs[2][SPB][HID];
    __shared__ __align__(16) float4 part[4][SPB][64];   // (r, z, n_i, n_h)
    __shared__ __align__(16) float  h1[SPB][HID];
    __shared__ __align__(16) float  h2[SPB][HID];

    const int tid  = threadIdx.x;
    const int wv   = tid >> 6;       // wave id 0..3  -> k-slice
    const int lane = tid & 63;       // j (hidden index / gate row)
    const int k0   = wv << 4;        // k-slice start
    const int b0   = blockIdx.x * SPB;

    // ---- per-lane register weight slices: rows (j, 64+j, 128+j), cols [k0,k0+16) ----
    float wr1[16], wz1[16], wn1[16], ur1[16], uz1[16], un1[16];
    float wr2[16], wz2[16], wn2[16], ur2[16], uz2[16], un2[16];
#pragma unroll
    for (int kk = 0; kk < 16; ++kk) {
        const int c = k0 + kk;
        wr1[kk] = w_ih1[(lane      ) * HID + c];
        wz1[kk] = w_ih1[(lane +  64) * HID + c];
        wn1[kk] = w_ih1[(lane + 128) * HID + c];
        ur1[kk] = w_hh1[(lane      ) * HID + c];
        uz1[kk] = w_hh1[(lane +  64) * HID + c];
        un1[kk] = w_hh1[(lane + 128) * HID + c];
        wr2[kk] = w_ih2[(lane      ) * HID + c];
        wz2[kk] = w_ih2[(lane +  64) * HID + c];
        wn2[kk] = w_ih2[(lane + 128) * HID + c];
        ur2[kk] = w_hh2[(lane      ) * HID + c];
        uz2[kk] = w_hh2[(lane +  64) * HID + c];
        un2[kk] = w_hh2[(lane + 128) * HID + c];
    }

    // biases for the reduce role (depend only on j = lane)
    const float brA = b_ih1[lane]       + b_hh1[lane];
    const float bzA = b_ih1[64 + lane]  + b_hh1[64 + lane];
    const float biA = b_ih1[128 + lane];
    const float bhA = b_hh1[128 + lane];
    const float brB = b_ih2[lane]       + b_hh2[lane];
    const float bzB = b_ih2[64 + lane]  + b_hh2[64 + lane];
    const float biB = b_ih2[128 + lane];
    const float bhB = b_hh2[128 + lane];

    // ---- init h = 0, load x[t=0] ----
    for (int i = tid; i < SPB * HID; i += NTHREADS) {
        (&h1[0][0])[i] = 0.0f;
        (&h2[0][0])[i] = 0.0f;
    }
    const int sp = tid >> 5;            // sample for x staging
    const int e  = (tid & 31) * 2;      // element pair
    const float* xsrc = state + (size_t)(b0 + sp) * T_STEPS * HID + e;
    {
        float2 v = *(const float2*)xsrc;
        *(float2*)&xs[0][sp][e] = v;
    }
    __syncthreads();

    int buf = 0;
    for (int t = 0; t < T_STEPS; ++t) {
        // prefetch next timestep's x into registers (hidden under phase A)
        float2 pf = make_float2(0.0f, 0.0f);
        if (t + 1 < T_STEPS)
            pf = *(const float2*)(xsrc + (size_t)(t + 1) * HID);

        // ---------------- layer 1: partial gate sums over this wave's k-slice ----------------
        for (int s = 0; s < SPB; ++s) {
            float r = 0.0f, z = 0.0f, ni = 0.0f, nh = 0.0f;
#pragma unroll
            for (int q = 0; q < 4; ++q) {
                const float4 xv = *(const float4*)&xs[buf][s][k0 + q * 4];
                const float4 hv = *(const float4*)&h1[s][k0 + q * 4];
                const int kk = q * 4;
                FMA4(r,  wr1, xv, kk)
                FMA4(r,  ur1, hv, kk)
                FMA4(z,  wz1, xv, kk)
                FMA4(z,  uz1, hv, kk)
                FMA4(ni, wn1, xv, kk)
                FMA4(nh, un1, hv, kk)
            }
            part[wv][s][lane] = make_float4(r, z, ni, nh);
        }
        __syncthreads();

        // ---------------- layer-1 reduce + gates + h1 update ----------------
#pragma unroll
        for (int rep = 0; rep < 2; ++rep) {
            const int s = wv + rep * 4;
            const float4 p0 = part[0][s][lane];
            const float4 p1 = part[1][s][lane];
            const float4 p2 = part[2][s][lane];
            const float4 p3 = part[3][s][lane];
            const float R  = p0.x + p1.x + p2.x + p3.x + brA;
            const float Z  = p0.y + p1.y + p2.y + p3.y + bzA;
            const float Ni = p0.z + p1.z + p2.z + p3.z + biA;
            const float Nh = p0.w + p1.w + p2.w + p3.w + bhA;
            const float rg = 1.0f / (1.0f + __expf(-R));
            const float zg = 1.0f / (1.0f + __expf(-Z));
            const float a  = Ni + rg * Nh;
            const float ng = 1.0f - 2.0f / (1.0f + __expf(2.0f * a));
            h1[s][lane] = (1.0f - zg) * ng + zg * h1[s][lane];
        }
        // stash prefetched x into the dead buffer (last read >=3 barriers ago)
        *(float2*)&xs[buf ^ 1][sp][e] = pf;
        __syncthreads();

        // ---------------- layer 2: input = new h1, hidden = h2 ----------------
        for (int s = 0; s < SPB; ++s) {
            float r = 0.0f, z = 0.0f, ni = 0.0f, nh = 0.0f;
#pragma unroll
            for (int q = 0; q < 4; ++q) {
                const float4 sv = *(const float4*)&h1[s][k0 + q * 4];
                const float4 hv = *(const float4*)&h2[s][k0 + q * 4];
                const int kk = q * 4;
                FMA4(r,  wr2, sv, kk)
                FMA4(r,  ur2, hv, kk)
                FMA4(z,  wz2, sv, kk)
                FMA4(z,  uz2, hv, kk)
                FMA4(ni, wn2, sv, kk)
                FMA4(nh, un2, hv, kk)
            }
            part[wv][s][lane] = make_float4(r, z, ni, nh);
        }
        __syncthreads();

        // ---------------- layer-2 reduce + gates + h2 update ----------------
#pragma unroll
        for (int rep = 0; rep < 2; ++rep) {
            const int s = wv + rep * 4;
            const float4 p0 = part[0][s][lane];
            const float4 p1 = part[1][s][lane];
            const float4 p2 = part[2][s][lane];
            const float4 p3 = part[3][s][lane];
            const float R  = p0.x + p1.x + p2.x + p3.x + brB;
            const float Z  = p0.y + p1.y + p2.y + p3.y + bzB;
            const float Ni = p0.z + p1.z + p2.z + p3.z + biB;
            const float Nh = p0.w + p1.w + p2.w + p3.w + bhB;
            const float rg = 1.0f / (1.0f + __expf(-R));
            const float zg = 1.0f / (1.0f + __expf(-Z));
            const float a  = Ni + rg * Nh;
            const float ng = 1.0f - 2.0f / (1.0f + __expf(2.0f * a));
            h2[s][lane] = (1.0f - zg) * ng + zg * h2[s][lane];
        }
        __syncthreads();

        buf ^= 1;
    }

    // ---------------- final FC: out[b][a] = fc_w[a,:] . h2[s,:] + fc_b[a] ----------------
    if (tid < 64) {
        const int s = tid >> 3, a = tid & 7;
        float acc = fc_b[a];
#pragma unroll
        for (int j = 0; j < HID; ++j)
            acc = fmaf(h2[s][j], fc_w[a * HID + j], acc);
        out[(size_t)(b0 + s) * 8 + a] = acc;
    }
}

extern "C" void kernel_launch(void* const* d_in, const int* in_sizes, int n_in,
                              void* d_out, int out_size, void* d_ws, size_t ws_size,
                              hipStream_t stream) {
    (void)in_sizes; (void)n_in; (void)d_ws; (void)ws_size; (void)out_size;
    const float* state = (const float*)d_in[0];
    const float* w_ih1 = (const float*)d_in[1];
    const float* w_hh1 = (const float*)d_in[2];
    const float* b_ih1 = (const float*)d_in[3];
    const float* b_hh1 = (const float*)d_in[4];
    const float* w_ih2 = (const float*)d_in[5];
    const float* w_hh2 = (const float*)d_in[6];
    const float* b_ih2 = (const float*)d_in[7];
    const float* b_hh2 = (const float*)d_in[8];
    const float* fc_w  = (const float*)d_in[9];
    const float* fc_b  = (const float*)d_in[10];
    float* out = (float*)d_out;

    dim3 grid(2048 / SPB);   // 256 blocks -> 1 per CU
    dim3 block(NTHREADS);
    gru2_fp32<<<grid, block, 0, stream>>>(state,
                                          w_ih1, w_hh1, b_ih1, b_hh1,
                                          w_ih2, w_hh2, b_ih2, b_hh2,
                                          fc_w, fc_b, out);
}

// Round 2
// 651.938 us; speedup vs baseline: 5.3719x; 5.3719x over previous
//
#include <hip/hip_runtime.h>

#define T_STEPS 512
#define HID 64
#define SPB 8
#define NT 256

typedef short bf16x8 __attribute__((ext_vector_type(8)));
typedef float f32x4 __attribute__((ext_vector_type(4)));

#define MFMA(a, b, c) __builtin_amdgcn_mfma_f32_16x16x32_bf16(a, b, c, 0, 0, 0)

__device__ __forceinline__ unsigned f2bf1(float f) {   // f32 -> bf16 bits, RNE
    unsigned u = __builtin_bit_cast(unsigned, f);
    u += 0x7FFFu + ((u >> 16) & 1u);
    return u >> 16;
}
__device__ __forceinline__ unsigned pack2(float a, float b) {
    return f2bf1(a) | (f2bf1(b) << 16);
}
__device__ __forceinline__ float bf2f(unsigned short h) {
    unsigned u = ((unsigned)h) << 16;
    return __builtin_bit_cast(float, u);
}
// LDS byte address for [sample][k] bf16 rows of 128B, XOR-swizzled (T2)
__device__ __forceinline__ char* swz(void* base, int s, int kbyte) {
    int off = s * 128 + kbyte;
    off ^= (s & 7) << 4;
    return (char*)base + off;
}
// gather 8 consecutive fp32 -> bf16x8 fragment
__device__ __forceinline__ bf16x8 g8row(const float* __restrict__ p) {
    bf16x8 r;
#pragma unroll
    for (int j = 0; j < 8; ++j) r[j] = (short)f2bf1(p[j]);
    return r;
}
__device__ __forceinline__ float sigm(float x) { return 1.0f / (1.0f + __expf(-x)); }
__device__ __forceinline__ float tanh_(float a) { return 1.0f - 2.0f / (1.0f + __expf(2.0f * a)); }

__global__ __launch_bounds__(NT, 1)
void gru2_mfma(const float* __restrict__ state,
               const float* __restrict__ w_ih1, const float* __restrict__ w_hh1,
               const float* __restrict__ b_ih1, const float* __restrict__ b_hh1,
               const float* __restrict__ w_ih2, const float* __restrict__ w_hh2,
               const float* __restrict__ b_ih2, const float* __restrict__ b_hh2,
               const float* __restrict__ fc_w,  const float* __restrict__ fc_b,
               float* __restrict__ out)
{
    // [sample][k] bf16, 128B rows, XOR-swizzled; double-buffered
    __shared__ __align__(16) unsigned short xb[2][16][64];
    __shared__ __align__(16) unsigned short h1b[2][16][64];
    __shared__ __align__(16) unsigned short h2b[2][16][64];

    const int tid  = threadIdx.x;
    const int w    = tid >> 6;      // wave id -> owns gate rows [16w,16w+16)
    const int lane = tid & 63;
    const int i16  = lane & 15;     // A-row / B-col(sample) / D-col
    const int g    = lane >> 4;     // 0..3
    const int g8   = g * 8;         // A/B k-element base within a 32-chunk
    const int b0   = blockIdx.x * SPB;

    // ---------------- resident weight A-fragments (96 VGPR) ----------------
    const int rA = (16 * w + i16) * HID;        // r rows
    const int zA = rA + 64 * HID;               // z rows
    const int nA = rA + 128 * HID;              // n rows
    bf16x8 ar1[4], az1[4], an1i[2], an1h[2];
    bf16x8 ar2[4], az2[4], an2i[2], an2h[2];
    ar1[0] = g8row(w_ih1 + rA + g8);      ar1[1] = g8row(w_ih1 + rA + 32 + g8);
    ar1[2] = g8row(w_hh1 + rA + g8);      ar1[3] = g8row(w_hh1 + rA + 32 + g8);
    az1[0] = g8row(w_ih1 + zA + g8);      az1[1] = g8row(w_ih1 + zA + 32 + g8);
    az1[2] = g8row(w_hh1 + zA + g8);      az1[3] = g8row(w_hh1 + zA + 32 + g8);
    an1i[0] = g8row(w_ih1 + nA + g8);     an1i[1] = g8row(w_ih1 + nA + 32 + g8);
    an1h[0] = g8row(w_hh1 + nA + g8);     an1h[1] = g8row(w_hh1 + nA + 32 + g8);
    ar2[0] = g8row(w_ih2 + rA + g8);      ar2[1] = g8row(w_ih2 + rA + 32 + g8);
    ar2[2] = g8row(w_hh2 + rA + g8);      ar2[3] = g8row(w_hh2 + rA + 32 + g8);
    az2[0] = g8row(w_ih2 + zA + g8);      az2[1] = g8row(w_ih2 + zA + 32 + g8);
    az2[2] = g8row(w_hh2 + zA + g8);      az2[3] = g8row(w_hh2 + zA + 32 + g8);
    an2i[0] = g8row(w_ih2 + nA + g8);     an2i[1] = g8row(w_ih2 + nA + 32 + g8);
    an2h[0] = g8row(w_hh2 + nA + g8);     an2h[1] = g8row(w_hh2 + nA + 32 + g8);

    // biases for D rows 16w + 4g + q
    float brA[4], bzA[4], biA[4], bhA[4], brB[4], bzB[4], biB[4], bhB[4];
#pragma unroll
    for (int q = 0; q < 4; ++q) {
        const int r0 = 16 * w + 4 * g + q;
        brA[q] = b_ih1[r0] + b_hh1[r0];
        bzA[q] = b_ih1[64 + r0] + b_hh1[64 + r0];
        biA[q] = b_ih1[128 + r0];
        bhA[q] = b_hh1[128 + r0];
        brB[q] = b_ih2[r0] + b_hh2[r0];
        bzB[q] = b_ih2[64 + r0] + b_hh2[64 + r0];
        biB[q] = b_ih2[128 + r0];
        bhB[q] = b_hh2[128 + r0];
    }

    // ---------------- zero LDS (samples 8..15 stay zero forever) ----------------
    for (int k = tid; k < 2 * 16 * 64; k += NT) {
        ((unsigned short*)xb)[k]  = 0;
        ((unsigned short*)h1b)[k] = 0;
        ((unsigned short*)h2b)[k] = 0;
    }

    // x staging role: thread -> (sample ss, k-pair sk)
    const int ss = tid >> 5;          // 0..7 (real samples only)
    const int sk = (tid & 31) * 2;    // k element
    const float* xgp = state + ((size_t)(b0 + ss) * T_STEPS) * HID + sk;
    {   // x_0 directly into xb[0]
        float2 v0 = *(const float2*)xgp;
        *(unsigned*)swz(xb[0], ss, sk * 2) = pack2(v0.x, v0.y);
    }
    float2 PF = *(const float2*)(xgp + HID);   // x_1 in flight
    __syncthreads();

    float h1r[4] = {0, 0, 0, 0}, h2r[4] = {0, 0, 0, 0};

#define STEP(CUR, TT)                                                           \
  {                                                                             \
    const int prv = (CUR) ^ 1;                                                  \
    bf16x8 bx0 = *(const bf16x8*)swz(xb[CUR], i16, g8 * 2);                     \
    bf16x8 bx1 = *(const bf16x8*)swz(xb[CUR], i16, 64 + g8 * 2);                \
    bf16x8 bh0 = *(const bf16x8*)swz(h1b[prv], i16, g8 * 2);                    \
    bf16x8 bh1 = *(const bf16x8*)swz(h1b[prv], i16, 64 + g8 * 2);               \
    f32x4 aR = {0,0,0,0}, aZ = {0,0,0,0}, aNi = {0,0,0,0}, aNh = {0,0,0,0};     \
    aR  = MFMA(ar1[0], bx0, aR);   aR  = MFMA(ar1[1], bx1, aR);                 \
    aR  = MFMA(ar1[2], bh0, aR);   aR  = MFMA(ar1[3], bh1, aR);                 \
    aZ  = MFMA(az1[0], bx0, aZ);   aZ  = MFMA(az1[1], bx1, aZ);                 \
    aZ  = MFMA(az1[2], bh0, aZ);   aZ  = MFMA(az1[3], bh1, aZ);                 \
    aNi = MFMA(an1i[0], bx0, aNi); aNi = MFMA(an1i[1], bx1, aNi);               \
    aNh = MFMA(an1h[0], bh0, aNh); aNh = MFMA(an1h[1], bh1, aNh);               \
    _Pragma("unroll")                                                           \
    for (int q = 0; q < 4; ++q) {                                               \
      float rg = sigm(aR[q] + brA[q]);                                          \
      float zg = sigm(aZ[q] + bzA[q]);                                          \
      float a  = aNi[q] + biA[q] + rg * (aNh[q] + bhA[q]);                      \
      float ng = tanh_(a);                                                      \
      h1r[q] = (1.0f - zg) * ng + zg * h1r[q];                                  \
    }                                                                           \
    *(uint2*)swz(h1b[CUR], i16, 32 * w + 8 * g) =                               \
        make_uint2(pack2(h1r[0], h1r[1]), pack2(h1r[2], h1r[3]));               \
    *(unsigned*)swz(xb[prv], ss, sk * 2) = pack2(PF.x, PF.y);                   \
    { int tld = (TT) + 2; if (tld > T_STEPS - 1) tld = T_STEPS - 1;             \
      PF = *(const float2*)(xgp + (size_t)tld * HID); }                         \
    __syncthreads();                                                            \
    bf16x8 c0 = *(const bf16x8*)swz(h1b[CUR], i16, g8 * 2);                     \
    bf16x8 c1 = *(const bf16x8*)swz(h1b[CUR], i16, 64 + g8 * 2);                \
    bf16x8 d0 = *(const bf16x8*)swz(h2b[prv], i16, g8 * 2);                     \
    bf16x8 d1 = *(const bf16x8*)swz(h2b[prv], i16, 64 + g8 * 2);                \
    f32x4 cR = {0,0,0,0}, cZ = {0,0,0,0}, cNi = {0,0,0,0}, cNh = {0,0,0,0};     \
    cR  = MFMA(ar2[0], c0, cR);   cR  = MFMA(ar2[1], c1, cR);                   \
    cR  = MFMA(ar2[2], d0, cR);   cR  = MFMA(ar2[3], d1, cR);                   \
    cZ  = MFMA(az2[0], c0, cZ);   cZ  = MFMA(az2[1], c1, cZ);                   \
    cZ  = MFMA(az2[2], d0, cZ);   cZ  = MFMA(az2[3], d1, cZ);                   \
    cNi = MFMA(an2i[0], c0, cNi); cNi = MFMA(an2i[1], c1, cNi);                 \
    cNh = MFMA(an2h[0], d0, cNh); cNh = MFMA(an2h[1], d1, cNh);                 \
    _Pragma("unroll")                                                           \
    for (int q = 0; q < 4; ++q) {                                               \
      float rg = sigm(cR[q] + brB[q]);                                          \
      float zg = sigm(cZ[q] + bzB[q]);                                          \
      float a  = cNi[q] + biB[q] + rg * (cNh[q] + bhB[q]);                      \
      float ng = tanh_(a);                                                      \
      h2r[q] = (1.0f - zg) * ng + zg * h2r[q];                                  \
    }                                                                           \
    *(uint2*)swz(h2b[CUR], i16, 32 * w + 8 * g) =                               \
        make_uint2(pack2(h2r[0], h2r[1]), pack2(h2r[2], h2r[3]));               \
    __syncthreads();                                                            \
  }

    for (int t = 0; t < T_STEPS; t += 2) {
        STEP(0, t)
        STEP(1, t + 1)
    }
#undef STEP

    // ---------------- final FC from h2b[1] (t=511 -> CUR=1) ----------------
    if (tid < 64) {
        const int s = tid >> 3, a = tid & 7;
        float acc = fc_b[a];
#pragma unroll
        for (int j = 0; j < HID; ++j) {
            unsigned short hv = *(unsigned short*)swz(h2b[1], s, j * 2);
            acc = fmaf(bf2f(hv), fc_w[a * HID + j], acc);
        }
        out[(size_t)(b0 + s) * 8 + a] = acc;
    }
}

extern "C" void kernel_launch(void* const* d_in, const int* in_sizes, int n_in,
                              void* d_out, int out_size, void* d_ws, size_t ws_size,
                              hipStream_t stream) {
    (void)in_sizes; (void)n_in; (void)d_ws; (void)ws_size; (void)out_size;
    const float* state = (const float*)d_in[0];
    const float* w_ih1 = (const float*)d_in[1];
    const float* w_hh1 = (const float*)d_in[2];
    const float* b_ih1 = (const float*)d_in[3];
    const float* b_hh1 = (const float*)d_in[4];
    const float* w_ih2 = (const float*)d_in[5];
    const float* w_hh2 = (const float*)d_in[6];
    const float* b_ih2 = (const float*)d_in[7];
    const float* b_hh2 = (const float*)d_in[8];
    const float* fc_w  = (const float*)d_in[9];
    const float* fc_b  = (const float*)d_in[10];
    float* out = (float*)d_out;

    dim3 grid(2048 / SPB);   // 256 blocks -> 1 per CU
    dim3 block(NT);
    gru2_mfma<<<grid, block, 0, stream>>>(state,
                                          w_ih1, w_hh1, b_ih1, b_hh1,
                                          w_ih2, w_hh2, b_ih2, b_hh2,
                                          fc_w, fc_b, out);
}

// Round 3
// 566.156 us; speedup vs baseline: 6.1858x; 1.1515x over previous
//
#include <hip/hip_runtime.h>

#define T_STEPS 512
#define HID 64
#define SPB 8
#define NT 512

typedef short bf16x8 __attribute__((ext_vector_type(8)));
typedef float f32x4 __attribute__((ext_vector_type(4)));

#define MFMA(a, b, c) __builtin_amdgcn_mfma_f32_16x16x32_bf16(a, b, c, 0, 0, 0)

__device__ __forceinline__ unsigned f2bf1(float f) {   // f32 -> bf16 bits, RNE
    unsigned u = __builtin_bit_cast(unsigned, f);
    u += 0x7FFFu + ((u >> 16) & 1u);
    return u >> 16;
}
__device__ __forceinline__ unsigned pack2(float a, float b) {
    return f2bf1(a) | (f2bf1(b) << 16);
}
__device__ __forceinline__ float bf2f(unsigned short h) {
    unsigned u = ((unsigned)h) << 16;
    return __builtin_bit_cast(float, u);
}
// LDS byte address for [sample][k] bf16 rows of 128B, XOR-swizzled (T2)
__device__ __forceinline__ char* swz(const void* base, int s, int kbyte) {
    int off = s * 128 + kbyte;
    off ^= (s & 7) << 4;
    return (char*)base + off;
}
// gather 8 consecutive fp32 -> bf16x8 fragment
__device__ __forceinline__ bf16x8 g8row(const float* __restrict__ p) {
    bf16x8 r;
#pragma unroll
    for (int j = 0; j < 8; ++j) r[j] = (short)f2bf1(p[j]);
    return r;
}
__device__ __forceinline__ float sigm(float x) { return 1.0f / (1.0f + __expf(-x)); }
__device__ __forceinline__ float tanh_(float a) { return 1.0f - 2.0f / (1.0f + __expf(2.0f * a)); }

// raw barrier: LDS writes drained, but NO vmcnt drain (keeps x prefetch in flight)
#define BAR() do { asm volatile("s_waitcnt lgkmcnt(0)" ::: "memory"); \
                   __builtin_amdgcn_s_barrier();                      \
                   asm volatile("" ::: "memory"); } while (0)

__global__ __launch_bounds__(NT, 1)
void gru2_pipe(const float* __restrict__ state,
               const float* __restrict__ w_ih1, const float* __restrict__ w_hh1,
               const float* __restrict__ b_ih1, const float* __restrict__ b_hh1,
               const float* __restrict__ w_ih2, const float* __restrict__ w_hh2,
               const float* __restrict__ b_ih2, const float* __restrict__ b_hh2,
               const float* __restrict__ fc_w,  const float* __restrict__ fc_b,
               float* __restrict__ out)
{
    // [sample][k] bf16, 128B rows, XOR-swizzled; double-buffered
    __shared__ __align__(16) unsigned short xb[2][16][64];
    __shared__ __align__(16) unsigned short h1b[2][16][64];
    __shared__ __align__(16) unsigned short h2b[2][16][64];

    const int tid  = threadIdx.x;
    const int wv8  = tid >> 6;        // 0..7
    const bool isA = wv8 < 4;         // waves 0-3: layer 1 @ t ; waves 4-7: layer 2 @ t-1
    const int w    = wv8 & 3;         // gate-row tile within the layer
    const int lane = tid & 63;
    const int i16  = lane & 15;       // sample col
    const int g    = lane >> 4;       // 0..3
    const int g8   = g * 8;
    const int b0   = blockIdx.x * SPB;

    // layer-specific weights/biases per wave-group (wave-uniform selects)
    const float* Wp = isA ? w_ih1 : w_ih2;    // multiplies operand P (x | h1)
    const float* Wq = isA ? w_hh1 : w_hh2;    // multiplies operand Q (h1prev | h2prev)
    const float* Bi = isA ? b_ih1 : b_ih2;
    const float* Bh = isA ? b_hh1 : b_hh2;

    // ---------------- resident weight A-fragments (48 VGPR) ----------------
    const int rA = (16 * w + i16) * HID;
    const int zA = rA + 64 * HID;
    const int nA = rA + 128 * HID;
    bf16x8 ar[4], az[4], ani[2], anh[2];
    ar[0]  = g8row(Wp + rA + g8);  ar[1]  = g8row(Wp + rA + 32 + g8);
    ar[2]  = g8row(Wq + rA + g8);  ar[3]  = g8row(Wq + rA + 32 + g8);
    az[0]  = g8row(Wp + zA + g8);  az[1]  = g8row(Wp + zA + 32 + g8);
    az[2]  = g8row(Wq + zA + g8);  az[3]  = g8row(Wq + zA + 32 + g8);
    ani[0] = g8row(Wp + nA + g8);  ani[1] = g8row(Wp + nA + 32 + g8);
    anh[0] = g8row(Wq + nA + g8);  anh[1] = g8row(Wq + nA + 32 + g8);

    float br[4], bz[4], bni[4], bnh[4];
#pragma unroll
    for (int q = 0; q < 4; ++q) {
        const int r0 = 16 * w + 4 * g + q;
        br[q]  = Bi[r0] + Bh[r0];
        bz[q]  = Bi[64 + r0] + Bh[64 + r0];
        bni[q] = Bi[128 + r0];
        bnh[q] = Bh[128 + r0];
    }

    // ---------------- zero LDS, then stage x(0), prefetch x(1) ----------------
    for (int k = tid; k < 2 * 16 * 64; k += NT) {
        ((unsigned short*)xb)[k]  = 0;
        ((unsigned short*)h1b)[k] = 0;
        ((unsigned short*)h2b)[k] = 0;
    }
    __syncthreads();   // zeroing fully done before staging overwrites xb[0]

    const int ss = tid >> 5;          // staging sample (valid for tid<256)
    const int sk = (tid & 31) * 2;    // staging k element
    const float* xgp = state + (size_t)(b0 + (ss & 7)) * T_STEPS * HID + sk;
    float2 PF = make_float2(0.0f, 0.0f);
    if (tid < 256) {
        float2 v0 = *(const float2*)xgp;
        *(unsigned*)swz(xb[0], ss, sk * 2) = pack2(v0.x, v0.y);
        PF = *(const float2*)(xgp + HID);          // x(1) in flight
    }
    __syncthreads();

    float hr[4] = {0, 0, 0, 0};       // A: h1 rows ; B: h2 rows (D-layout)

#define ITER(TT, CUR)                                                            \
  {                                                                              \
    const int prv = (CUR) ^ 1;                                                   \
    const bool active = isA ? ((TT) < T_STEPS) : ((TT) >= 1);                    \
    if (active) {                                                                \
      const unsigned short (*P)[64] = isA ? xb[CUR]  : h1b[prv];                 \
      const unsigned short (*Q)[64] = isA ? h1b[prv] : h2b[CUR];                 \
      unsigned short (*D)[64]       = isA ? h1b[CUR] : h2b[prv];                 \
      bf16x8 p0 = *(const bf16x8*)swz(P, i16, g8 * 2);                           \
      bf16x8 p1 = *(const bf16x8*)swz(P, i16, 64 + g8 * 2);                      \
      bf16x8 q0 = *(const bf16x8*)swz(Q, i16, g8 * 2);                           \
      bf16x8 q1 = *(const bf16x8*)swz(Q, i16, 64 + g8 * 2);                      \
      f32x4 aR = {0,0,0,0}, aZ = {0,0,0,0}, aNi = {0,0,0,0}, aNh = {0,0,0,0};    \
      aR  = MFMA(ar[0], p0, aR);   aR  = MFMA(ar[1], p1, aR);                    \
      aR  = MFMA(ar[2], q0, aR);   aR  = MFMA(ar[3], q1, aR);                    \
      aZ  = MFMA(az[0], p0, aZ);   aZ  = MFMA(az[1], p1, aZ);                    \
      aZ  = MFMA(az[2], q0, aZ);   aZ  = MFMA(az[3], q1, aZ);                    \
      aNi = MFMA(ani[0], p0, aNi); aNi = MFMA(ani[1], p1, aNi);                  \
      aNh = MFMA(anh[0], q0, aNh); aNh = MFMA(anh[1], q1, aNh);                  \
      _Pragma("unroll")                                                          \
      for (int q = 0; q < 4; ++q) {                                              \
        float rg = sigm(aR[q] + br[q]);                                          \
        float zg = sigm(aZ[q] + bz[q]);                                          \
        float a  = aNi[q] + bni[q] + rg * (aNh[q] + bnh[q]);                     \
        float ng = tanh_(a);                                                     \
        hr[q] = (1.0f - zg) * ng + zg * hr[q];                                   \
      }                                                                          \
      *(uint2*)swz(D, i16, 32 * w + 8 * g) =                                     \
          make_uint2(pack2(hr[0], hr[1]), pack2(hr[2], hr[3]));                  \
    }                                                                            \
    if (tid < 256 && (TT) < T_STEPS) {                                           \
      *(unsigned*)swz(xb[prv], ss, sk * 2) = pack2(PF.x, PF.y);                  \
      int tld = (TT) + 2; if (tld > T_STEPS - 1) tld = T_STEPS - 1;              \
      PF = *(const float2*)(xgp + (size_t)tld * HID);                            \
    }                                                                            \
    BAR();                                                                       \
  }

    for (int t = 0; t < T_STEPS; t += 2) {
        ITER(t, 0)
        ITER(t + 1, 1)
    }
    ITER(T_STEPS, 0)      // drain: layer 2 computes h2(511)
#undef ITER

    // ---------------- final FC from h2b[1] (u=511 -> buffer 511&1) ----------------
    if (tid < 64) {
        const int s = tid >> 3, a = tid & 7;
        float acc = fc_b[a];
#pragma unroll
        for (int j = 0; j < HID; ++j) {
            unsigned short hv = *(unsigned short*)swz(h2b[1], s, j * 2);
            acc = fmaf(bf2f(hv), fc_w[a * HID + j], acc);
        }
        out[(size_t)(b0 + s) * 8 + a] = acc;
    }
}

extern "C" void kernel_launch(void* const* d_in, const int* in_sizes, int n_in,
                              void* d_out, int out_size, void* d_ws, size_t ws_size,
                              hipStream_t stream) {
    (void)in_sizes; (void)n_in; (void)d_ws; (void)ws_size; (void)out_size;
    const float* state = (const float*)d_in[0];
    const float* w_ih1 = (const float*)d_in[1];
    const float* w_hh1 = (const float*)d_in[2];
    const float* b_ih1 = (const float*)d_in[3];
    const float* b_hh1 = (const float*)d_in[4];
    const float* w_ih2 = (const float*)d_in[5];
    const float* w_hh2 = (const float*)d_in[6];
    const float* b_ih2 = (const float*)d_in[7];
    const float* b_hh2 = (const float*)d_in[8];
    const float* fc_w  = (const float*)d_in[9];
    const float* fc_b  = (const float*)d_in[10];
    float* out = (float*)d_out;

    dim3 grid(2048 / SPB);   // 256 blocks -> 1 per CU, 8 waves = 2/SIMD
    dim3 block(NT);
    gru2_pipe<<<grid, block, 0, stream>>>(state,
                                          w_ih1, w_hh1, b_ih1, b_hh1,
                                          w_ih2, w_hh2, b_ih2, b_hh2,
                                          fc_w, fc_b, out);
}

// Round 4
// 289.819 us; speedup vs baseline: 12.0838x; 1.9535x over previous
//
#include <hip/hip_runtime.h>

#define T_STEPS 512
#define HID 64
#define SPB 8
#define NT 512

typedef short bf16x8 __attribute__((ext_vector_type(8)));
typedef float f32x4 __attribute__((ext_vector_type(4)));

#define MFMA(a, b, c) __builtin_amdgcn_mfma_f32_16x16x32_bf16(a, b, c, 0, 0, 0)

__device__ __forceinline__ unsigned f2bf1(float f) {   // init-path only
    unsigned u = __builtin_bit_cast(unsigned, f);
    u += 0x7FFFu + ((u >> 16) & 1u);
    return u >> 16;
}
__device__ __forceinline__ unsigned cvtpk(float lo, float hi) {  // 1 instr pack
    unsigned r;
    asm("v_cvt_pk_bf16_f32 %0, %1, %2" : "=v"(r) : "v"(lo), "v"(hi));
    return r;
}
__device__ __forceinline__ float bf2f(unsigned short h) {
    unsigned u = ((unsigned)h) << 16;
    return __builtin_bit_cast(float, u);
}
// LDS byte address for [sample][k] bf16 rows of 128B, XOR-swizzled (T2)
__device__ __forceinline__ char* swz(const void* base, int s, int kbyte) {
    int off = s * 128 + kbyte;
    off ^= (s & 7) << 4;
    return (char*)base + off;
}
__device__ __forceinline__ bf16x8 g8row(const float* __restrict__ p) {
    bf16x8 r;
#pragma unroll
    for (int j = 0; j < 8; ++j) r[j] = (short)f2bf1(p[j]);
    return r;
}

// raw barrier: LDS drained, NO vmcnt drain (x prefetch stays in flight)
#define BAR() do { asm volatile("s_waitcnt lgkmcnt(0)" ::: "memory"); \
                   __builtin_amdgcn_s_barrier();                      \
                   asm volatile("" ::: "memory"); } while (0)

__global__ __launch_bounds__(NT, 1)
void gru2_diet(const float* __restrict__ state,
               const float* __restrict__ w_ih1, const float* __restrict__ w_hh1,
               const float* __restrict__ b_ih1, const float* __restrict__ b_hh1,
               const float* __restrict__ w_ih2, const float* __restrict__ w_hh2,
               const float* __restrict__ b_ih2, const float* __restrict__ b_hh2,
               const float* __restrict__ fc_w,  const float* __restrict__ fc_b,
               float* __restrict__ out)
{
    __shared__ __align__(16) unsigned short xb[2][16][64];
    __shared__ __align__(16) unsigned short h1b[2][16][64];
    __shared__ __align__(16) unsigned short h2b[2][16][64];

    const int tid  = threadIdx.x;
    const int wv8  = tid >> 6;
    const bool isA = wv8 < 4;         // waves 0-3: layer1 @ t ; 4-7: layer2 @ t-1
    const int w    = wv8 & 3;
    const int lane = tid & 63;
    const int i16  = lane & 15;
    const int g    = lane >> 4;
    const int g8   = g * 8;
    const int b0   = blockIdx.x * SPB;

    const float* Wp = isA ? w_ih1 : w_ih2;
    const float* Wq = isA ? w_hh1 : w_hh2;
    const float* Bi = isA ? b_ih1 : b_ih2;
    const float* Bh = isA ? b_hh1 : b_hh2;

    // resident weight A-fragments
    const int rA = (16 * w + i16) * HID;
    const int zA = rA + 64 * HID;
    const int nA = rA + 128 * HID;
    bf16x8 ar[4], az[4], ani[2], anh[2];
    ar[0]  = g8row(Wp + rA + g8);  ar[1]  = g8row(Wp + rA + 32 + g8);
    ar[2]  = g8row(Wq + rA + g8);  ar[3]  = g8row(Wq + rA + 32 + g8);
    az[0]  = g8row(Wp + zA + g8);  az[1]  = g8row(Wp + zA + 32 + g8);
    az[2]  = g8row(Wq + zA + g8);  az[3]  = g8row(Wq + zA + 32 + g8);
    ani[0] = g8row(Wp + nA + g8);  ani[1] = g8row(Wp + nA + 32 + g8);
    anh[0] = g8row(Wq + nA + g8);  anh[1] = g8row(Wq + nA + 32 + g8);

    // biases as D-layout f32x4 -> used as MFMA C-init (zero-cost bias add)
    f32x4 bR4, bZ4, bNi4, bNh4;
#pragma unroll
    for (int q = 0; q < 4; ++q) {
        const int r0 = 16 * w + 4 * g + q;
        bR4[q]  = Bi[r0] + Bh[r0];
        bZ4[q]  = Bi[64 + r0] + Bh[64 + r0];
        bNi4[q] = Bi[128 + r0];
        bNh4[q] = Bh[128 + r0];
    }

    // ---- precomputed LDS addresses (parity-indexed, compile-time idx) ----
    // A: P=xb[c], Q=h1b[c^1], D=h1b[c];  B: P=h1b[c^1], Q=h2b[c], D=h2b[c^1]
    char* rp[2][2]; char* rq[2][2]; char* wd[2]; char* sa[2];
#pragma unroll
    for (int c = 0; c < 2; ++c) {
        const void* Pb = isA ? (const void*)xb[c]      : (const void*)h1b[c ^ 1];
        const void* Qb = isA ? (const void*)h1b[c ^ 1] : (const void*)h2b[c];
        void* Db       = isA ? (void*)h1b[c]           : (void*)h2b[c ^ 1];
        rp[c][0] = swz(Pb, i16, 16 * g);
        rp[c][1] = swz(Pb, i16, 64 + 16 * g);
        rq[c][0] = swz(Qb, i16, 16 * g);
        rq[c][1] = swz(Qb, i16, 64 + 16 * g);
        wd[c]    = swz(Db, i16, 32 * w + 8 * g);
        sa[c]    = swz(xb[c ^ 1], (tid >> 5) & 7, (tid & 31) * 4);
    }

    // zero LDS, then stage x(0), prefetch x(1)
    for (int k = tid; k < 2 * 16 * 64; k += NT) {
        ((unsigned short*)xb)[k]  = 0;
        ((unsigned short*)h1b)[k] = 0;
        ((unsigned short*)h2b)[k] = 0;
    }
    __syncthreads();

    const int ss = (tid >> 5) & 7;
    const int sk = (tid & 31) * 2;
    const float* xgp = state + (size_t)(b0 + ss) * T_STEPS * HID + sk;
    float2 PF = make_float2(0.0f, 0.0f);
    if (tid < 256) {
        float2 v0 = *(const float2*)xgp;
        *(unsigned*)swz(xb[0], ss, sk * 2) = cvtpk(v0.x, v0.y);
        PF = *(const float2*)(xgp + HID);          // x(1) in flight
    }
    const float* xnext = xgp + 2 * HID;            // x(2) next
    __syncthreads();

    float hr[4] = {0, 0, 0, 0};

#define ITER(TT, CUR)                                                            \
  {                                                                              \
    const bool active = isA ? ((TT) < T_STEPS) : ((TT) >= 1);                    \
    if (active) {                                                                \
      bf16x8 p0 = *(const bf16x8*)rp[CUR][0];                                    \
      bf16x8 p1 = *(const bf16x8*)rp[CUR][1];                                    \
      bf16x8 q0 = *(const bf16x8*)rq[CUR][0];                                    \
      bf16x8 q1 = *(const bf16x8*)rq[CUR][1];                                    \
      f32x4 aR  = MFMA(ar[0], p0, bR4);                                          \
      f32x4 aZ  = MFMA(az[0], p0, bZ4);                                          \
      f32x4 aNi = MFMA(ani[0], p0, bNi4);                                        \
      f32x4 aNh = MFMA(anh[0], q0, bNh4);                                        \
      aR  = MFMA(ar[1], p1, aR);   aR  = MFMA(ar[2], q0, aR);                    \
      aR  = MFMA(ar[3], q1, aR);                                                 \
      aZ  = MFMA(az[1], p1, aZ);   aZ  = MFMA(az[2], q0, aZ);                    \
      aZ  = MFMA(az[3], q1, aZ);                                                 \
      aNi = MFMA(ani[1], p1, aNi);                                               \
      aNh = MFMA(anh[1], q1, aNh);                                               \
      _Pragma("unroll")                                                          \
      for (int q = 0; q < 4; ++q) {                                              \
        float rg = __builtin_amdgcn_rcpf(1.0f + __expf(-aR[q]));                 \
        float zg = __builtin_amdgcn_rcpf(1.0f + __expf(-aZ[q]));                 \
        float nn = fmaf(rg, aNh[q], aNi[q]);                                     \
        float ng = fmaf(-2.0f,                                                   \
                        __builtin_amdgcn_rcpf(1.0f + __expf(2.0f * nn)), 1.0f);  \
        hr[q] = fmaf(zg, hr[q] - ng, ng);                                        \
      }                                                                          \
      *(uint2*)wd[CUR] = make_uint2(cvtpk(hr[0], hr[1]), cvtpk(hr[2], hr[3]));   \
    }                                                                            \
    if (tid < 256 && (TT) < T_STEPS) {                                           \
      *(unsigned*)sa[CUR] = cvtpk(PF.x, PF.y);                                   \
      PF = *(const float2*)xnext;                                                \
      xnext += ((TT) <= T_STEPS - 4) ? HID : 0;                                  \
    }                                                                            \
    BAR();                                                                       \
  }

    for (int t = 0; t < T_STEPS; t += 2) {
        ITER(t, 0)
        ITER(t + 1, 1)
    }
    ITER(T_STEPS, 0)      // drain: layer 2 computes h2(511)
#undef ITER

    // final FC from h2b[1]
    if (tid < 64) {
        const int s = tid >> 3, a = tid & 7;
        float acc = fc_b[a];
#pragma unroll
        for (int j = 0; j < HID; ++j) {
            unsigned short hv = *(unsigned short*)swz(h2b[1], s, j * 2);
            acc = fmaf(bf2f(hv), fc_w[a * HID + j], acc);
        }
        out[(size_t)(b0 + s) * 8 + a] = acc;
    }
}

extern "C" void kernel_launch(void* const* d_in, const int* in_sizes, int n_in,
                              void* d_out, int out_size, void* d_ws, size_t ws_size,
                              hipStream_t stream) {
    (void)in_sizes; (void)n_in; (void)d_ws; (void)ws_size; (void)out_size;
    const float* state = (const float*)d_in[0];
    const float* w_ih1 = (const float*)d_in[1];
    const float* w_hh1 = (const float*)d_in[2];
    const float* b_ih1 = (const float*)d_in[3];
    const float* b_hh1 = (const float*)d_in[4];
    const float* w_ih2 = (const float*)d_in[5];
    const float* w_hh2 = (const float*)d_in[6];
    const float* b_ih2 = (const float*)d_in[7];
    const float* b_hh2 = (const float*)d_in[8];
    const float* fc_w  = (const float*)d_in[9];
    const float* fc_b  = (const float*)d_in[10];
    float* out = (float*)d_out;

    dim3 grid(2048 / SPB);   // 256 blocks -> 1 per CU, 8 waves = 2/SIMD
    dim3 block(NT);
    gru2_diet<<<grid, block, 0, stream>>>(state,
                                          w_ih1, w_hh1, b_ih1, b_hh1,
                                          w_ih2, w_hh2, b_ih2, b_hh2,
                                          fc_w, fc_b, out);
}

// Round 5
// 269.115 us; speedup vs baseline: 13.0135x; 1.0769x over previous
//
#include <hip/hip_runtime.h>

#define T_STEPS 512
#define HID 64
#define SPB 8
#define NT 512

typedef short bf16x8 __attribute__((ext_vector_type(8)));
typedef float f32x4 __attribute__((ext_vector_type(4)));

#define MFMA(a, b, c) __builtin_amdgcn_mfma_f32_16x16x32_bf16(a, b, c, 0, 0, 0)

#define LOG2E 1.44269504088896340736f

__device__ __forceinline__ unsigned f2bf1(float f) {   // init-path only
    unsigned u = __builtin_bit_cast(unsigned, f);
    u += 0x7FFFu + ((u >> 16) & 1u);
    return u >> 16;
}
__device__ __forceinline__ unsigned cvtpk(float lo, float hi) {  // 1 instr pack
    unsigned r;
    asm("v_cvt_pk_bf16_f32 %0, %1, %2" : "=v"(r) : "v"(lo), "v"(hi));
    return r;
}
__device__ __forceinline__ float bf2f(unsigned short h) {
    unsigned u = ((unsigned)h) << 16;
    return __builtin_bit_cast(float, u);
}
// LDS byte address for [sample][k] bf16 rows of 128B, XOR-swizzled (T2)
__device__ __forceinline__ char* swz(const void* base, int s, int kbyte) {
    int off = s * 128 + kbyte;
    off ^= (s & 7) << 4;
    return (char*)base + off;
}
// gather 8 consecutive fp32, scale, -> bf16x8 fragment (init path)
__device__ __forceinline__ bf16x8 g8rowS(const float* __restrict__ p, float s) {
    bf16x8 r;
#pragma unroll
    for (int j = 0; j < 8; ++j) r[j] = (short)f2bf1(p[j] * s);
    return r;
}

// raw barrier: LDS drained, NO vmcnt drain (x prefetch stays in flight)
#define BAR() do { asm volatile("s_waitcnt lgkmcnt(0)" ::: "memory"); \
                   __builtin_amdgcn_s_barrier();                      \
                   asm volatile("" ::: "memory"); } while (0)

__global__ __launch_bounds__(NT, 1)
void gru2_lean(const float* __restrict__ state,
               const float* __restrict__ w_ih1, const float* __restrict__ w_hh1,
               const float* __restrict__ b_ih1, const float* __restrict__ b_hh1,
               const float* __restrict__ w_ih2, const float* __restrict__ w_hh2,
               const float* __restrict__ b_ih2, const float* __restrict__ b_hh2,
               const float* __restrict__ fc_w,  const float* __restrict__ fc_b,
               float* __restrict__ out)
{
    __shared__ __align__(16) unsigned short xb[2][16][64];
    __shared__ __align__(16) unsigned short h1b[2][16][64];
    __shared__ __align__(16) unsigned short h2b[2][16][64];

    const int tid  = threadIdx.x;
    const int wv8  = tid >> 6;
    const bool isA = wv8 < 4;         // waves 0-3: layer1 @ t ; 4-7: layer2 @ t-1
    const int w    = wv8 & 3;
    const int lane = tid & 63;
    const int i16  = lane & 15;
    const int g    = lane >> 4;
    const int g8   = g * 8;
    const int b0   = blockIdx.x * SPB;
    const bool realc = (i16 < 8);     // this lane's MFMA column is a real sample

    const float* Wp = isA ? w_ih1 : w_ih2;
    const float* Wq = isA ? w_hh1 : w_hh2;
    const float* Bi = isA ? b_ih1 : b_ih2;
    const float* Bh = isA ? b_hh1 : b_hh2;

    // resident weight A-fragments, exp-scale folded in:
    //   r,z rows * -log2e  (sigmoid -> exp2 direct)
    //   n rows  * 2*log2e  (tanh    -> exp2 direct)
    const int rA = (16 * w + i16) * HID;
    const int zA = rA + 64 * HID;
    const int nA = rA + 128 * HID;
    bf16x8 ar[4], az[4], ani[2], anh[2];
    ar[0]  = g8rowS(Wp + rA + g8, -LOG2E);  ar[1]  = g8rowS(Wp + rA + 32 + g8, -LOG2E);
    ar[2]  = g8rowS(Wq + rA + g8, -LOG2E);  ar[3]  = g8rowS(Wq + rA + 32 + g8, -LOG2E);
    az[0]  = g8rowS(Wp + zA + g8, -LOG2E);  az[1]  = g8rowS(Wp + zA + 32 + g8, -LOG2E);
    az[2]  = g8rowS(Wq + zA + g8, -LOG2E);  az[3]  = g8rowS(Wq + zA + 32 + g8, -LOG2E);
    ani[0] = g8rowS(Wp + nA + g8, 2.0f * LOG2E);
    ani[1] = g8rowS(Wp + nA + 32 + g8, 2.0f * LOG2E);
    anh[0] = g8rowS(Wq + nA + g8, 2.0f * LOG2E);
    anh[1] = g8rowS(Wq + nA + 32 + g8, 2.0f * LOG2E);

    // biases as D-layout f32x4 C-init, same scales
    f32x4 bR4, bZ4, bNi4, bNh4;
#pragma unroll
    for (int q = 0; q < 4; ++q) {
        const int r0 = 16 * w + 4 * g + q;
        bR4[q]  = -LOG2E * (Bi[r0] + Bh[r0]);
        bZ4[q]  = -LOG2E * (Bi[64 + r0] + Bh[64 + r0]);
        bNi4[q] = 2.0f * LOG2E * Bi[128 + r0];
        bNh4[q] = 2.0f * LOG2E * Bh[128 + r0];
    }

    // ---- precomputed LDS addresses (parity-indexed) ----
    char* rp[2][2]; char* rq[2][2]; char* wd[2]; char* sa[2];
#pragma unroll
    for (int c = 0; c < 2; ++c) {
        const void* Pb = isA ? (const void*)xb[c]      : (const void*)h1b[c ^ 1];
        const void* Qb = isA ? (const void*)h1b[c ^ 1] : (const void*)h2b[c];
        void* Db       = isA ? (void*)h1b[c]           : (void*)h2b[c ^ 1];
        rp[c][0] = swz(Pb, i16, 16 * g);
        rp[c][1] = swz(Pb, i16, 64 + 16 * g);
        rq[c][0] = swz(Qb, i16, 16 * g);
        rq[c][1] = swz(Qb, i16, 64 + 16 * g);
        wd[c]    = swz(Db, i16, 32 * w + 8 * g);
        sa[c]    = swz(xb[c ^ 1], (tid >> 5) & 7, (tid & 31) * 4);
    }

    // zero LDS, then stage x(0), prefetch x(1)
    for (int k = tid; k < 2 * 16 * 64; k += NT) {
        ((unsigned short*)xb)[k]  = 0;
        ((unsigned short*)h1b)[k] = 0;
        ((unsigned short*)h2b)[k] = 0;
    }
    __syncthreads();

    const int ss = (tid >> 5) & 7;
    const int sk = (tid & 31) * 2;
    const float* xgp = state + (size_t)(b0 + ss) * T_STEPS * HID + sk;
    float2 PF = make_float2(0.0f, 0.0f);
    if (tid < 256) {
        float2 v0 = *(const float2*)xgp;
        *(unsigned*)swz(xb[0], ss, sk * 2) = cvtpk(v0.x, v0.y);
        PF = *(const float2*)(xgp + HID);          // x(1) in flight
    }
    const float* xnext = xgp + 2 * HID;            // x(2) next
    __syncthreads();

    float hr[4] = {0, 0, 0, 0};
    // B-fragments persist across iters so phantom lanes carry defined (stale) values
    bf16x8 p0 = {}, p1 = {}, q0 = {}, q1 = {};

#define ITER(TT, CUR)                                                            \
  {                                                                              \
    const bool active = isA ? ((TT) < T_STEPS) : ((TT) >= 1);                    \
    if (active) {                                                                \
      if (realc) {   /* only real-sample columns read: halves LDS delivery */    \
        p0 = *(const bf16x8*)rp[CUR][0];                                         \
        p1 = *(const bf16x8*)rp[CUR][1];                                         \
        q0 = *(const bf16x8*)rq[CUR][0];                                         \
        q1 = *(const bf16x8*)rq[CUR][1];                                         \
      }                                                                          \
      f32x4 aR  = MFMA(ar[0], p0, bR4);                                          \
      f32x4 aZ  = MFMA(az[0], p0, bZ4);                                          \
      f32x4 aNi = MFMA(ani[0], p0, bNi4);                                        \
      f32x4 aNh = MFMA(anh[0], q0, bNh4);                                        \
      aR  = MFMA(ar[1], p1, aR);   aR  = MFMA(ar[2], q0, aR);                    \
      aR  = MFMA(ar[3], q1, aR);                                                 \
      aZ  = MFMA(az[1], p1, aZ);   aZ  = MFMA(az[2], q0, aZ);                    \
      aZ  = MFMA(az[3], q1, aZ);                                                 \
      aNi = MFMA(ani[1], p1, aNi);                                               \
      aNh = MFMA(anh[1], q1, aNh);                                               \
      _Pragma("unroll")                                                          \
      for (int q = 0; q < 4; ++q) {                                              \
        float rg = __builtin_amdgcn_rcpf(1.0f + __builtin_amdgcn_exp2f(aR[q]));  \
        float zg = __builtin_amdgcn_rcpf(1.0f + __builtin_amdgcn_exp2f(aZ[q]));  \
        float e2 = __builtin_amdgcn_exp2f(fmaf(rg, aNh[q], aNi[q]));             \
        float ng = fmaf(-2.0f, __builtin_amdgcn_rcpf(1.0f + e2), 1.0f);          \
        hr[q] = fmaf(zg, hr[q] - ng, ng);                                        \
      }                                                                          \
      if (realc)                                                                 \
        *(uint2*)wd[CUR] = make_uint2(cvtpk(hr[0], hr[1]), cvtpk(hr[2], hr[3])); \
    }                                                                            \
    if (tid < 256 && (TT) < T_STEPS) {                                           \
      *(unsigned*)sa[CUR] = cvtpk(PF.x, PF.y);                                   \
      PF = *(const float2*)xnext;                                                \
      xnext += ((TT) <= T_STEPS - 4) ? HID : 0;                                  \
    }                                                                            \
    BAR();                                                                       \
  }

    for (int t = 0; t < T_STEPS; t += 2) {
        ITER(t, 0)
        ITER(t + 1, 1)
    }
    ITER(T_STEPS, 0)      // drain: layer 2 computes h2(511)
#undef ITER

    // final FC from h2b[1]
    if (tid < 64) {
        const int s = tid >> 3, a = tid & 7;
        float acc = fc_b[a];
#pragma unroll
        for (int j = 0; j < HID; ++j) {
            unsigned short hv = *(unsigned short*)swz(h2b[1], s, j * 2);
            acc = fmaf(bf2f(hv), fc_w[a * HID + j], acc);
        }
        out[(size_t)(b0 + s) * 8 + a] = acc;
    }
}

extern "C" void kernel_launch(void* const* d_in, const int* in_sizes, int n_in,
                              void* d_out, int out_size, void* d_ws, size_t ws_size,
                              hipStream_t stream) {
    (void)in_sizes; (void)n_in; (void)d_ws; (void)ws_size; (void)out_size;
    const float* state = (const float*)d_in[0];
    const float* w_ih1 = (const float*)d_in[1];
    const float* w_hh1 = (const float*)d_in[2];
    const float* b_ih1 = (const float*)d_in[3];
    const float* b_hh1 = (const float*)d_in[4];
    const float* w_ih2 = (const float*)d_in[5];
    const float* w_hh2 = (const float*)d_in[6];
    const float* b_ih2 = (const float*)d_in[7];
    const float* b_hh2 = (const float*)d_in[8];
    const float* fc_w  = (const float*)d_in[9];
    const float* fc_b  = (const float*)d_in[10];
    float* out = (float*)d_out;

    dim3 grid(2048 / SPB);   // 256 blocks -> 1 per CU, 8 waves = 2/SIMD
    dim3 block(NT);
    gru2_lean<<<grid, block, 0, stream>>>(state,
                                          w_ih1, w_hh1, b_ih1, b_hh1,
                                          w_ih2, w_hh2, b_ih2, b_hh2,
                                          fc_w, fc_b, out);
}

// Round 6
// 233.272 us; speedup vs baseline: 15.0131x; 1.1537x over previous
//
#include <hip/hip_runtime.h>

#define T_STEPS 512
#define HID 64
#define SPB 8
#define NT 512

typedef short bf16x8 __attribute__((ext_vector_type(8)));
typedef float f32x4 __attribute__((ext_vector_type(4)));

#define MFMA(a, b, c) __builtin_amdgcn_mfma_f32_16x16x32_bf16(a, b, c, 0, 0, 0)

#define LOG2E 1.44269504088896340736f

__device__ __forceinline__ unsigned f2bf1(float f) {   // init-path only
    unsigned u = __builtin_bit_cast(unsigned, f);
    u += 0x7FFFu + ((u >> 16) & 1u);
    return u >> 16;
}
__device__ __forceinline__ unsigned cvtpk(float lo, float hi) {  // 1 instr pack
    unsigned r;
    asm("v_cvt_pk_bf16_f32 %0, %1, %2" : "=v"(r) : "v"(lo), "v"(hi));
    return r;
}
__device__ __forceinline__ float bf2f(unsigned short h) {
    unsigned u = ((unsigned)h) << 16;
    return __builtin_bit_cast(float, u);
}
// lane <- lane^8 within each 16-lane row (full-rate VALU DPP row_ror:8)
__device__ __forceinline__ float dpp_ror8(float x) {
    int i = __builtin_bit_cast(int, x);
    int r = __builtin_amdgcn_mov_dpp(i, 0x128, 0xF, 0xF, true);
    return __builtin_bit_cast(float, r);
}
// LDS byte address for [sample][k] bf16 rows of 128B, XOR-swizzled (T2)
__device__ __forceinline__ char* swz(const void* base, int s, int kbyte) {
    int off = s * 128 + kbyte;
    off ^= (s & 7) << 4;
    return (char*)base + off;
}
// gather 8 consecutive fp32, scale, -> bf16x8 fragment (init path)
__device__ __forceinline__ bf16x8 g8rowS(const float* __restrict__ p, float s) {
    bf16x8 r;
#pragma unroll
    for (int j = 0; j < 8; ++j) r[j] = (short)f2bf1(p[j] * s);
    return r;
}

// raw barrier: LDS drained, NO vmcnt drain (x prefetch stays in flight)
#define BAR() do { asm volatile("s_waitcnt lgkmcnt(0)" ::: "memory"); \
                   __builtin_amdgcn_s_barrier();                      \
                   asm volatile("" ::: "memory"); } while (0)

__global__ __launch_bounds__(NT, 1)
void gru2_dpp(const float* __restrict__ state,
              const float* __restrict__ w_ih1, const float* __restrict__ w_hh1,
              const float* __restrict__ b_ih1, const float* __restrict__ b_hh1,
              const float* __restrict__ w_ih2, const float* __restrict__ w_hh2,
              const float* __restrict__ b_ih2, const float* __restrict__ b_hh2,
              const float* __restrict__ fc_w,  const float* __restrict__ fc_b,
              float* __restrict__ out)
{
    __shared__ __align__(16) unsigned short xb[2][16][64];
    __shared__ __align__(16) unsigned short h1b[2][16][64];
    __shared__ __align__(16) unsigned short h2b[2][16][64];

    const int tid  = threadIdx.x;
    const int wv8  = tid >> 6;
    const bool isA = wv8 < 4;         // waves 0-3: layer1 @ t ; 4-7: layer2 @ t-1
    const int w    = wv8 & 3;
    const int lane = tid & 63;
    const int i16  = lane & 15;
    const int g    = lane >> 4;
    const int g8   = g * 8;
    const int b0   = blockIdx.x * SPB;
    const bool realc = (i16 < 8);     // this lane's MFMA column is a real sample

    const float* Wp = isA ? w_ih1 : w_ih2;
    const float* Wq = isA ? w_hh1 : w_hh2;
    const float* Bi = isA ? b_ih1 : b_ih2;
    const float* Bh = isA ? b_hh1 : b_hh2;

    // resident weight A-fragments, exp-scale folded in
    const int rA = (16 * w + i16) * HID;
    const int zA = rA + 64 * HID;
    const int nA = rA + 128 * HID;
    bf16x8 ar[4], az[4], ani[2], anh[2];
    ar[0]  = g8rowS(Wp + rA + g8, -LOG2E);  ar[1]  = g8rowS(Wp + rA + 32 + g8, -LOG2E);
    ar[2]  = g8rowS(Wq + rA + g8, -LOG2E);  ar[3]  = g8rowS(Wq + rA + 32 + g8, -LOG2E);
    az[0]  = g8rowS(Wp + zA + g8, -LOG2E);  az[1]  = g8rowS(Wp + zA + 32 + g8, -LOG2E);
    az[2]  = g8rowS(Wq + zA + g8, -LOG2E);  az[3]  = g8rowS(Wq + zA + 32 + g8, -LOG2E);
    ani[0] = g8rowS(Wp + nA + g8, 2.0f * LOG2E);
    ani[1] = g8rowS(Wp + nA + 32 + g8, 2.0f * LOG2E);
    anh[0] = g8rowS(Wq + nA + g8, 2.0f * LOG2E);
    anh[1] = g8rowS(Wq + nA + 32 + g8, 2.0f * LOG2E);

    // biases as D-layout f32x4 C-init (per-row; neighbor lanes inherit correct rows)
    f32x4 bR4, bZ4, bNi4, bNh4;
#pragma unroll
    for (int q = 0; q < 4; ++q) {
        const int r0 = 16 * w + 4 * g + q;
        bR4[q]  = -LOG2E * (Bi[r0] + Bh[r0]);
        bZ4[q]  = -LOG2E * (Bi[64 + r0] + Bh[64 + r0]);
        bNi4[q] = 2.0f * LOG2E * Bi[128 + r0];
        bNh4[q] = 2.0f * LOG2E * Bh[128 + r0];
    }

    // ---- precomputed LDS addresses (parity-indexed) ----
    // reads: B-fragments (realc lanes only). writes: per-lane 1 dword, 2 rows.
    char* rp[2][2]; char* rq[2][2]; char* wd[2]; char* sa[2];
    const int scol = i16 & 7;                 // real sample column this lane owns
    const int qb4  = realc ? 0 : 4;           // byte offset: rows {0,1} or {2,3}
#pragma unroll
    for (int c = 0; c < 2; ++c) {
        const void* Pb = isA ? (const void*)xb[c]      : (const void*)h1b[c ^ 1];
        const void* Qb = isA ? (const void*)h1b[c ^ 1] : (const void*)h2b[c];
        void* Db       = isA ? (void*)h1b[c]           : (void*)h2b[c ^ 1];
        rp[c][0] = swz(Pb, i16, 16 * g);
        rp[c][1] = swz(Pb, i16, 64 + 16 * g);
        rq[c][0] = swz(Qb, i16, 16 * g);
        rq[c][1] = swz(Qb, i16, 64 + 16 * g);
        wd[c]    = swz(Db, scol, 32 * w + 8 * g + qb4);
        sa[c]    = swz(xb[c ^ 1], (tid >> 5) & 7, (tid & 31) * 4);
    }

    // zero LDS, then stage x(0), prefetch x(1)
    for (int k = tid; k < 2 * 16 * 64; k += NT) {
        ((unsigned short*)xb)[k]  = 0;
        ((unsigned short*)h1b)[k] = 0;
        ((unsigned short*)h2b)[k] = 0;
    }
    __syncthreads();

    const int ss = (tid >> 5) & 7;
    const int sk = (tid & 31) * 2;
    const float* xgp = state + (size_t)(b0 + ss) * T_STEPS * HID + sk;
    float2 PF = make_float2(0.0f, 0.0f);
    if (tid < 256) {
        float2 v0 = *(const float2*)xgp;
        *(unsigned*)swz(xb[0], ss, sk * 2) = cvtpk(v0.x, v0.y);
        PF = *(const float2*)(xgp + HID);          // x(1) in flight
    }
    const float* xnext = xgp + 2 * HID;            // x(2) next
    __syncthreads();

    float hr0 = 0.0f, hr1 = 0.0f;   // this lane's 2 h rows (rows qb..qb+1 of col scol)
    // B-fragments persist across iters so phantom lanes carry defined (stale) values
    bf16x8 p0 = {}, p1 = {}, q0 = {}, q1 = {};

#define ITER(TT, CUR)                                                            \
  {                                                                              \
    const bool active = isA ? ((TT) < T_STEPS) : ((TT) >= 1);                    \
    if (active) {                                                                \
      if (realc) {   /* only real-sample columns read: halves LDS delivery */    \
        p0 = *(const bf16x8*)rp[CUR][0];                                         \
        p1 = *(const bf16x8*)rp[CUR][1];                                         \
        q0 = *(const bf16x8*)rq[CUR][0];                                         \
        q1 = *(const bf16x8*)rq[CUR][1];                                         \
      }                                                                          \
      __builtin_amdgcn_s_setprio(1);                                             \
      f32x4 aR  = MFMA(ar[0], p0, bR4);                                          \
      f32x4 aZ  = MFMA(az[0], p0, bZ4);                                          \
      f32x4 aNi = MFMA(ani[0], p0, bNi4);                                        \
      f32x4 aNh = MFMA(anh[0], q0, bNh4);                                        \
      aR  = MFMA(ar[1], p1, aR);   aR  = MFMA(ar[2], q0, aR);                    \
      aR  = MFMA(ar[3], q1, aR);                                                 \
      aZ  = MFMA(az[1], p1, aZ);   aZ  = MFMA(az[2], q0, aZ);                    \
      aZ  = MFMA(az[3], q1, aZ);                                                 \
      aNi = MFMA(ani[1], p1, aNi);                                               \
      aNh = MFMA(anh[1], q1, aNh);                                               \
      __builtin_amdgcn_s_setprio(0);                                             \
      /* repack: phantom-col lanes take rows {2,3} of col i16-8 via dpp ror8 */  \
      float vR0  = realc ? aR[0]  : dpp_ror8(aR[2]);                             \
      float vR1  = realc ? aR[1]  : dpp_ror8(aR[3]);                             \
      float vZ0  = realc ? aZ[0]  : dpp_ror8(aZ[2]);                             \
      float vZ1  = realc ? aZ[1]  : dpp_ror8(aZ[3]);                             \
      float vNi0 = realc ? aNi[0] : dpp_ror8(aNi[2]);                            \
      float vNi1 = realc ? aNi[1] : dpp_ror8(aNi[3]);                            \
      float vNh0 = realc ? aNh[0] : dpp_ror8(aNh[2]);                            \
      float vNh1 = realc ? aNh[1] : dpp_ror8(aNh[3]);                            \
      {                                                                          \
        float rg0 = __builtin_amdgcn_rcpf(1.0f + __builtin_amdgcn_exp2f(vR0));   \
        float zg0 = __builtin_amdgcn_rcpf(1.0f + __builtin_amdgcn_exp2f(vZ0));   \
        float e20 = __builtin_amdgcn_exp2f(fmaf(rg0, vNh0, vNi0));               \
        float ng0 = fmaf(-2.0f, __builtin_amdgcn_rcpf(1.0f + e20), 1.0f);        \
        hr0 = fmaf(zg0, hr0 - ng0, ng0);                                         \
        float rg1 = __builtin_amdgcn_rcpf(1.0f + __builtin_amdgcn_exp2f(vR1));   \
        float zg1 = __builtin_amdgcn_rcpf(1.0f + __builtin_amdgcn_exp2f(vZ1));   \
        float e21 = __builtin_amdgcn_exp2f(fmaf(rg1, vNh1, vNi1));               \
        float ng1 = fmaf(-2.0f, __builtin_amdgcn_rcpf(1.0f + e21), 1.0f);        \
        hr1 = fmaf(zg1, hr1 - ng1, ng1);                                         \
      }                                                                          \
      *(unsigned*)wd[CUR] = cvtpk(hr0, hr1);                                     \
    }                                                                            \
    if (tid < 256 && (TT) < T_STEPS) {                                           \
      *(unsigned*)sa[CUR] = cvtpk(PF.x, PF.y);                                   \
      PF = *(const float2*)xnext;                                                \
      xnext += ((TT) <= T_STEPS - 4) ? HID : 0;                                  \
    }                                                                            \
    BAR();                                                                       \
  }

    for (int t = 0; t < T_STEPS; t += 2) {
        ITER(t, 0)
        ITER(t + 1, 1)
    }
    ITER(T_STEPS, 0)      // drain: layer 2 computes h2(511)
#undef ITER

    // final FC from h2b[1]
    if (tid < 64) {
        const int s = tid >> 3, a = tid & 7;
        float acc = fc_b[a];
#pragma unroll
        for (int j = 0; j < HID; ++j) {
            unsigned short hv = *(unsigned short*)swz(h2b[1], s, j * 2);
            acc = fmaf(bf2f(hv), fc_w[a * HID + j], acc);
        }
        out[(size_t)(b0 + s) * 8 + a] = acc;
    }
}

extern "C" void kernel_launch(void* const* d_in, const int* in_sizes, int n_in,
                              void* d_out, int out_size, void* d_ws, size_t ws_size,
                              hipStream_t stream) {
    (void)in_sizes; (void)n_in; (void)d_ws; (void)ws_size; (void)out_size;
    const float* state = (const float*)d_in[0];
    const float* w_ih1 = (const float*)d_in[1];
    const float* w_hh1 = (const float*)d_in[2];
    const float* b_ih1 = (const float*)d_in[3];
    const float* b_hh1 = (const float*)d_in[4];
    const float* w_ih2 = (const float*)d_in[5];
    const float* w_hh2 = (const float*)d_in[6];
    const float* b_ih2 = (const float*)d_in[7];
    const float* b_hh2 = (const float*)d_in[8];
    const float* fc_w  = (const float*)d_in[9];
    const float* fc_b  = (const float*)d_in[10];
    float* out = (float*)d_out;

    dim3 grid(2048 / SPB);   // 256 blocks -> 1 per CU, 8 waves = 2/SIMD
    dim3 block(NT);
    gru2_dpp<<<grid, block, 0, stream>>>(state,
                                         w_ih1, w_hh1, b_ih1, b_hh1,
                                         w_ih2, w_hh2, b_ih2, b_hh2,
                                         fc_w, fc_b, out);
}